// Round 4
// baseline (190.406 us; speedup 1.0000x reference)
//
#include <hip/hip_runtime.h>
#include <stdint.h>

// MHA fused: qkv = x @ w_qkv ; attention ; out [b,s,E] fp32
// Round 4: (1) GEMM epilogue restaged through LDS -> coalesced ushort8 stores
//   (Q/K to row-major C[4096][2048]; V transposed to VT[bh][64][2048]).
// (2) attn: swapped QK^T (S^T = mfma(K,Q)) -> P kept in registers, packed to
//   bf16 and redistributed to the PV A-fragment via ds_bpermute; no P LDS.

typedef __attribute__((ext_vector_type(8))) short v8s;   // 8 x bf16 (4 VGPR)
typedef __attribute__((ext_vector_type(4))) float v4f;   // MFMA accum

__device__ __forceinline__ unsigned short bf16bits(float f) {
  union { float f; unsigned int u; } c; c.f = f;
  unsigned int u = c.u;
  unsigned int r = (u + 0x7fffu + ((u >> 16) & 1u)) >> 16;  // RNE
  return (unsigned short)r;
}

__device__ __forceinline__ v4f mfma16(v8s a, v8s b, v4f c) {
  return __builtin_amdgcn_mfma_f32_16x16x32_bf16(a, b, c, 0, 0, 0);
}

// async global->LDS, 16B per lane; lds dest must be wave-uniform base.
#define GLD16(g, l) __builtin_amdgcn_global_load_lds( \
    (const __attribute__((address_space(1))) unsigned int*)(g), \
    (__attribute__((address_space(3))) unsigned int*)(l), 16, 0, 0)

// ---------------- prep: x fp32 -> bf16 ----------------
__global__ __launch_bounds__(256) void cvt_x_kernel(const float4* __restrict__ x4,
                                                    ushort4* __restrict__ o4, int n4) {
  int i = blockIdx.x * 256 + threadIdx.x;
  if (i < n4) {
    float4 v = x4[i];
    ushort4 o;
    o.x = bf16bits(v.x); o.y = bf16bits(v.y); o.z = bf16bits(v.z); o.w = bf16bits(v.w);
    o4[i] = o;
  }
}

// ---------------- prep: w [1024][3072] f32 -> wT [3072][1024] bf16 ----------------
__global__ __launch_bounds__(256) void cvt_wT_kernel(const float* __restrict__ w,
                                                     unsigned short* __restrict__ wt) {
  __shared__ float t[32][33];
  int n0 = blockIdx.x * 32, k0 = blockIdx.y * 32;
  int tx = threadIdx.x & 31, ty = threadIdx.x >> 5;  // 32 x 8
  for (int i = 0; i < 4; ++i) {
    int kr = ty + i * 8;
    t[kr][tx] = w[(k0 + kr) * 3072 + n0 + tx];
  }
  __syncthreads();
  for (int i = 0; i < 4; ++i) {
    int nr = ty + i * 8;
    wt[(n0 + nr) * 1024 + k0 + tx] = bf16bits(t[tx][nr]);
  }
}

// ---------------- QKV GEMM ----------------
// A = x_bf [4096][1024], B = wT [3072][1024]. Tile 128x128, BK=64, 4 waves 2x2.
// bn<16: C rows coalesced into Cq[4096][2048] (Q cols 0-1023, K 1024-2047).
// bn>=16: transposed restage -> VT[bh][64][2048].
__global__ __launch_bounds__(256) void qkv_gemm(const unsigned short* __restrict__ A,
                                                const unsigned short* __restrict__ Bm,
                                                unsigned short* __restrict__ Cq,
                                                unsigned short* __restrict__ VTh) {
  __shared__ __align__(16) unsigned short S[128 * 128];  // 32KB: staging + C restage
  unsigned short* As = S;
  unsigned short* Bs = S + 128 * 64;
  int bm = blockIdx.x, bn = blockIdx.y;
  int tid = threadIdx.x, lane = tid & 63, wave = tid >> 6;
  int wr = wave >> 1, wc = wave & 1;

  v4f acc[4][4];
  for (int i = 0; i < 4; ++i)
    for (int j = 0; j < 4; ++j) acc[i][j] = (v4f){0.f, 0.f, 0.f, 0.f};

  for (int kk = 0; kk < 1024; kk += 64) {
    __syncthreads();
    for (int i = 0; i < 4; ++i) {               // A tile: 128 rows x 8 chunks
      int e = i * 256 + tid;
      int row = e >> 3, cc = e & 7;
      int sc = cc ^ (row & 7);                  // pre-swizzled source
      GLD16(A + (bm * 128 + row) * 1024 + kk + sc * 8,
            (char*)As + (i * 256 + wave * 64) * 16);
    }
    for (int i = 0; i < 4; ++i) {               // B tile
      int e = i * 256 + tid;
      int row = e >> 3, cc = e & 7;
      int sc = cc ^ (row & 7);
      GLD16(Bm + (bn * 128 + row) * 1024 + kk + sc * 8,
            (char*)Bs + (i * 256 + wave * 64) * 16);
    }
    __syncthreads();
    for (int ks = 0; ks < 2; ++ks) {
      v8s af[4], bf[4];
      for (int rt = 0; rt < 4; ++rt) {
        int ra = wr * 64 + rt * 16 + (lane & 15);
        int ca = (ks * 4 + (lane >> 4)) ^ (ra & 7);
        af[rt] = *(const v8s*)&As[ra * 64 + ca * 8];
      }
      for (int ct = 0; ct < 4; ++ct) {
        int rb = wc * 64 + ct * 16 + (lane & 15);
        int cb = (ks * 4 + (lane >> 4)) ^ (rb & 7);
        bf[ct] = *(const v8s*)&Bs[rb * 64 + cb * 8];
      }
      for (int rt = 0; rt < 4; ++rt)
        for (int ct = 0; ct < 4; ++ct)
          acc[rt][ct] = mfma16(af[rt], bf[ct], acc[rt][ct]);
    }
  }

  __syncthreads();                              // staging reads done; reuse S as C tile
  if (bn < 16) {
    // row-major restage, chunk XOR (col>>3)^(m&7); then coalesced 16B row stores
    for (int ct = 0; ct < 4; ++ct) {
      int col = wc * 64 + ct * 16 + (lane & 15);
      for (int rt = 0; rt < 4; ++rt)
        for (int j = 0; j < 4; ++j) {
          int m = wr * 64 + rt * 16 + ((lane >> 4) << 2) + j;
          S[m * 128 + (((col >> 3) ^ (m & 7)) << 3) + (col & 7)] = bf16bits(acc[rt][ct][j]);
        }
    }
    __syncthreads();
    for (int i = 0; i < 8; ++i) {
      int c = i * 256 + tid;                    // 2048 chunks: 128 rows x 16
      int m = c >> 4, c8 = c & 15;
      v8s v = *(const v8s*)&S[m * 128 + ((c8 ^ (m & 7)) << 3)];
      *(v8s*)&Cq[(size_t)(bm * 128 + m) * 2048 + bn * 128 + c8 * 8] = v;
    }
  } else {
    // transposed restage: ST[n][m], chunk XOR (m>>3)^(n&7); rows of m = s
    for (int ct = 0; ct < 4; ++ct) {
      int n = wc * 64 + ct * 16 + (lane & 15);
      for (int rt = 0; rt < 4; ++rt) {
        int m0 = wr * 64 + rt * 16 + ((lane >> 4) << 2);
        ushort4 p4;
        p4.x = bf16bits(acc[rt][ct][0]); p4.y = bf16bits(acc[rt][ct][1]);
        p4.z = bf16bits(acc[rt][ct][2]); p4.w = bf16bits(acc[rt][ct][3]);
        *(ushort4*)&S[n * 128 + (((m0 >> 3) ^ (n & 7)) << 3) + (m0 & 7)] = p4;
      }
    }
    __syncthreads();
    int b = bm >> 4, s0 = (bm & 15) * 128;
    for (int i = 0; i < 8; ++i) {
      int c = i * 256 + tid;                    // 2048 chunks: 128 n x 16 m-chunks
      int n = c >> 4, c8 = c & 15;
      v8s v = *(const v8s*)&S[n * 128 + ((c8 ^ (n & 7)) << 3)];
      int nn = bn * 128 + n - 2048;             // v-col 0..1023
      int head = nn >> 6, d = nn & 63;
      *(v8s*)&VTh[(size_t)((b * 16 + head) * 64 + d) * 2048 + s0 + c8 * 8] = v;
    }
  }
}

// ---------------- attention: per (bh, 64 q-rows) block ----------------
// 4 waves x 16 q-rows. KBLK=64. Swapped QK^T: S^T=mfma(K,Q) -> lane owns
// q=lane&15, 16 keys; exp+pack in-register; PV A-frag built via ds_bpermute.
__global__ __launch_bounds__(256) void attn_kernel(const unsigned short* __restrict__ Cq,
                                                   const unsigned short* __restrict__ VTh,
                                                   float* __restrict__ out) {
  __shared__ __align__(16) unsigned short Qs[64 * 64];   // [q][d]
  __shared__ __align__(16) unsigned short Ks[64 * 64];   // [key][d]
  __shared__ __align__(16) unsigned short Vs[64 * 64];   // [d][key]
  int qb = blockIdx.x, bh = blockIdx.y;
  int tid = threadIdx.x, lane = tid & 63, wave = tid >> 6;
  int wq = wave * 16;
  int b = bh >> 4, h = bh & 15;

  const unsigned short* Qg = Cq + (size_t)(b * 2048 + qb * 64) * 2048 + h * 64;
  const unsigned short* Kg = Cq + (size_t)(b * 2048) * 2048 + 1024 + h * 64;
  const unsigned short* Vg = VTh + (size_t)bh * 64 * 2048;

  for (int i = 0; i < 2; ++i) {                  // Q tile 64x64, swizzled fill
    int e = i * 256 + tid;
    int row = e >> 3, cc = e & 7;
    int sc = cc ^ (row & 7);
    GLD16(Qg + (size_t)row * 2048 + sc * 8, (char*)Qs + (i * 256 + wave * 64) * 16);
  }
  __syncthreads();

  v8s qf[2];
  for (int ks = 0; ks < 2; ++ks) {
    int rq = wq + (lane & 15);
    int cq = (ks * 4 + (lane >> 4)) ^ (rq & 7);
    qf[ks] = *(const v8s*)&Qs[rq * 64 + cq * 8];
  }

  v4f oacc[4];
  for (int j = 0; j < 4; ++j) oacc[j] = (v4f){0.f, 0.f, 0.f, 0.f};
  float rsum = 0.f;

  int sA = (lane & 15) + ((lane & 16) << 1);     // (lane&15) + 32*(g&1)
  int sB = sA + 16;
  bool hi = (lane >= 32);                        // g>>1

  for (int kt = 0; kt < 32; ++kt) {
    __syncthreads();                             // prior reads of Ks/Vs done
    for (int i = 0; i < 2; ++i) {                // K tile 64x64
      int e = i * 256 + tid;
      int row = e >> 3, cc = e & 7;
      int sc = cc ^ (row & 7);
      GLD16(Kg + (size_t)(kt * 64 + row) * 2048 + sc * 8,
            (char*)Ks + (i * 256 + wave * 64) * 16);
    }
    for (int i = 0; i < 2; ++i) {                // VT tile: rows d, 64-key slice
      int e = i * 256 + tid;
      int row = e >> 3, cc = e & 7;
      int sc = cc ^ (row & 7);
      GLD16(Vg + row * 2048 + kt * 64 + sc * 8, (char*)Vs + (i * 256 + wave * 64) * 16);
    }
    __syncthreads();

    // S^T = K . Q^T per key-tile: lane holds q=wq+(lane&15), keys ct*16+g*4+j
    v4f st[4];
    for (int j = 0; j < 4; ++j) st[j] = (v4f){0.f, 0.f, 0.f, 0.f};
    for (int ks = 0; ks < 2; ++ks) {
      v8s kf[4];
      for (int ct = 0; ct < 4; ++ct) {
        int rk = ct * 16 + (lane & 15);
        int ck = (ks * 4 + (lane >> 4)) ^ (rk & 7);
        kf[ct] = *(const v8s*)&Ks[rk * 64 + ck * 8];
      }
      for (int ct = 0; ct < 4; ++ct)
        st[ct] = mfma16(kf[ct], qf[ks], st[ct]);
    }

    // exp + pack to bf16 pairs: pk[ct][r] = keys ct*16+4g+2r,2r+1
    unsigned int pk[4][2];
#pragma unroll
    for (int ct = 0; ct < 4; ++ct) {
      float p0 = __expf(st[ct][0] * 0.03125f);
      float p1 = __expf(st[ct][1] * 0.03125f);
      float p2 = __expf(st[ct][2] * 0.03125f);
      float p3 = __expf(st[ct][3] * 0.03125f);
      rsum += (p0 + p1) + (p2 + p3);
      pk[ct][0] = (unsigned int)bf16bits(p0) | ((unsigned int)bf16bits(p1) << 16);
      pk[ct][1] = (unsigned int)bf16bits(p2) | ((unsigned int)bf16bits(p3) << 16);
    }

    // PV A-fragments: word w of lane <- src lane {sA,sB}, reg pk[2*ks4+hi][w&1]
    union U { unsigned int u[4]; v8s v; };
    U u0, u1;
    {
      unsigned int a0 = __shfl(pk[0][0], sA, 64), b0 = __shfl(pk[1][0], sA, 64);
      unsigned int a1 = __shfl(pk[0][1], sA, 64), b1 = __shfl(pk[1][1], sA, 64);
      unsigned int a2 = __shfl(pk[0][0], sB, 64), b2 = __shfl(pk[1][0], sB, 64);
      unsigned int a3 = __shfl(pk[0][1], sB, 64), b3 = __shfl(pk[1][1], sB, 64);
      u0.u[0] = hi ? b0 : a0; u0.u[1] = hi ? b1 : a1;
      u0.u[2] = hi ? b2 : a2; u0.u[3] = hi ? b3 : a3;
    }
    {
      unsigned int a0 = __shfl(pk[2][0], sA, 64), b0 = __shfl(pk[3][0], sA, 64);
      unsigned int a1 = __shfl(pk[2][1], sA, 64), b1 = __shfl(pk[3][1], sA, 64);
      unsigned int a2 = __shfl(pk[2][0], sB, 64), b2 = __shfl(pk[3][0], sB, 64);
      unsigned int a3 = __shfl(pk[2][1], sB, 64), b3 = __shfl(pk[3][1], sB, 64);
      u1.u[0] = hi ? b0 : a0; u1.u[1] = hi ? b1 : a1;
      u1.u[2] = hi ? b2 : a2; u1.u[3] = hi ? b3 : a3;
    }

    // O += P . V
#pragma unroll
    for (int ks4 = 0; ks4 < 2; ++ks4) {
      v8s pa = ks4 ? u1.v : u0.v;
      v8s vb[4];
      for (int dt = 0; dt < 4; ++dt) {
        int rv = dt * 16 + (lane & 15);
        int cv = (ks4 * 4 + (lane >> 4)) ^ (rv & 7);
        vb[dt] = *(const v8s*)&Vs[rv * 64 + cv * 8];
      }
      for (int dt = 0; dt < 4; ++dt)
        oacc[dt] = mfma16(pa, vb[dt], oacc[dt]);
    }
  }

  // total row sums: lanes {l, l^16, l^32, l^48} hold q=wq+(l&15)'s partials
  float rtot = rsum;
  rtot += __shfl_xor(rtot, 16, 64);
  rtot += __shfl_xor(rtot, 32, 64);
  float inv[4];
#pragma unroll
  for (int j = 0; j < 4; ++j)
    inv[j] = 1.f / __shfl(rtot, ((lane >> 4) << 2) + j, 64);

  for (int dt = 0; dt < 4; ++dt) {
    int q = qb * 64 + wq + ((lane >> 4) << 2);
    int d = h * 64 + dt * 16 + (lane & 15);
    for (int j = 0; j < 4; ++j)
      out[(size_t)(b * 2048 + q + j) * 1024 + d] = oacc[dt][j] * inv[j];
  }
}

extern "C" void kernel_launch(void* const* d_in, const int* in_sizes, int n_in,
                              void* d_out, int out_size, void* d_ws, size_t ws_size,
                              hipStream_t stream) {
  const float* x = (const float*)d_in[0];   // [2,2048,1024]
  const float* w = (const float*)d_in[1];   // [1024,3072]
  float* out = (float*)d_out;

  char* ws = (char*)d_ws;
  unsigned short* xb = (unsigned short*)ws;                  // [4096][1024] bf16, 8 MB
  unsigned short* wT = (unsigned short*)(ws + 8388608);      // [3072][1024] bf16, 6 MB
  unsigned short* Cq = (unsigned short*)(ws + 14680064);     // [4096][2048] bf16, 16 MB (Q|K)
  unsigned short* VT = (unsigned short*)(ws + 31457280);     // [32][64][2048] bf16, 8 MB

  cvt_x_kernel<<<4096, 256, 0, stream>>>((const float4*)x, (ushort4*)xb, 1048576);
  cvt_wT_kernel<<<dim3(96, 32), 256, 0, stream>>>(w, wT);
  qkv_gemm<<<dim3(32, 24), 256, 0, stream>>>(xb, wT, Cq, VT);
  attn_kernel<<<dim3(32, 32), 256, 0, stream>>>(Cq, VT, out);
}

// Round 5
// 189.610 us; speedup vs baseline: 1.0042x; 1.0042x over previous
//
#include <hip/hip_runtime.h>
#include <stdint.h>

// MHA fused: qkv = x @ w_qkv ; attention ; out [b,s,E] fp32
// Round 5: 2-phase stage-ahead pipelines (T3 minimum recipe) in both hot
// kernels. GEMM: 64x128 tile, dbuf LDS, 1 barrier/iter. attn: round-3 LDS-P
// softmax (shfl version reverted) + K/V dbuf stage-ahead + trunc P-pack.

typedef __attribute__((ext_vector_type(8))) short v8s;   // 8 x bf16 (4 VGPR)
typedef __attribute__((ext_vector_type(4))) float v4f;   // MFMA accum

__device__ __forceinline__ unsigned short bf16bits(float f) {
  union { float f; unsigned int u; } c; c.f = f;
  unsigned int u = c.u;
  unsigned int r = (u + 0x7fffu + ((u >> 16) & 1u)) >> 16;  // RNE
  return (unsigned short)r;
}

__device__ __forceinline__ v4f mfma16(v8s a, v8s b, v4f c) {
  return __builtin_amdgcn_mfma_f32_16x16x32_bf16(a, b, c, 0, 0, 0);
}

// async global->LDS, 16B per lane; lds dest must be wave-uniform base.
#define GLD16(g, l) __builtin_amdgcn_global_load_lds( \
    (const __attribute__((address_space(1))) unsigned int*)(g), \
    (__attribute__((address_space(3))) unsigned int*)(l), 16, 0, 0)

// ---------------- prep: x fp32 -> bf16 ----------------
__global__ __launch_bounds__(256) void cvt_x_kernel(const float4* __restrict__ x4,
                                                    ushort4* __restrict__ o4, int n4) {
  int i = blockIdx.x * 256 + threadIdx.x;
  if (i < n4) {
    float4 v = x4[i];
    ushort4 o;
    o.x = bf16bits(v.x); o.y = bf16bits(v.y); o.z = bf16bits(v.z); o.w = bf16bits(v.w);
    o4[i] = o;
  }
}

// ---------------- prep: w [1024][3072] f32 -> wT [3072][1024] bf16 ----------------
__global__ __launch_bounds__(256) void cvt_wT_kernel(const float* __restrict__ w,
                                                     unsigned short* __restrict__ wt) {
  __shared__ float t[32][33];
  int n0 = blockIdx.x * 32, k0 = blockIdx.y * 32;
  int tx = threadIdx.x & 31, ty = threadIdx.x >> 5;  // 32 x 8
  for (int i = 0; i < 4; ++i) {
    int kr = ty + i * 8;
    t[kr][tx] = w[(k0 + kr) * 3072 + n0 + tx];
  }
  __syncthreads();
  for (int i = 0; i < 4; ++i) {
    int nr = ty + i * 8;
    wt[(n0 + nr) * 1024 + k0 + tx] = bf16bits(t[tx][nr]);
  }
}

// ---------------- QKV GEMM ----------------
// A = x_bf [4096][1024], B = wT [3072][1024]. Tile 64x128, BK=64, 4 waves 2x2
// (wave = 32x64). Double-buffered LDS, stage-ahead, one barrier per K-step.
// bn<16: C -> Cq[4096][2048] (Q cols 0-1023, K 1024-2047). bn>=16: VT restage.
__global__ __launch_bounds__(256) void qkv_gemm(const unsigned short* __restrict__ A,
                                                const unsigned short* __restrict__ Bm,
                                                unsigned short* __restrict__ Cq,
                                                unsigned short* __restrict__ VTh) {
  // halves: As(h)=S+h*12288, Bs(h)=As+4096. 24576 elems = 48 KB.
  __shared__ __align__(16) unsigned short S[24576];
  int bm = blockIdx.x, bn = blockIdx.y;
  int tid = threadIdx.x, lane = tid & 63, wave = tid >> 6;
  int wr = wave >> 1, wc = wave & 1;

  v4f acc[2][4];
  for (int i = 0; i < 2; ++i)
    for (int j = 0; j < 4; ++j) acc[i][j] = (v4f){0.f, 0.f, 0.f, 0.f};

  auto STAGE = [&](int h, int kk) {
    unsigned short* As = S + h * 12288;
    unsigned short* Bs = As + 4096;
    for (int i = 0; i < 2; ++i) {               // A: 64 rows x 8 chunks
      int e = i * 256 + tid;
      int row = e >> 3, cc = e & 7;
      int sc = cc ^ (row & 7);
      GLD16(A + (bm * 64 + row) * 1024 + kk + sc * 8,
            (char*)As + (i * 256 + wave * 64) * 16);
    }
    for (int i = 0; i < 4; ++i) {               // B: 128 rows x 8 chunks
      int e = i * 256 + tid;
      int row = e >> 3, cc = e & 7;
      int sc = cc ^ (row & 7);
      GLD16(Bm + (bn * 128 + row) * 1024 + kk + sc * 8,
            (char*)Bs + (i * 256 + wave * 64) * 16);
    }
  };
  auto COMPUTE = [&](int h) {
    const unsigned short* As = S + h * 12288;
    const unsigned short* Bs = As + 4096;
    for (int ks = 0; ks < 2; ++ks) {
      v8s af[2], bf[4];
      for (int rt = 0; rt < 2; ++rt) {
        int ra = wr * 32 + rt * 16 + (lane & 15);
        int ca = (ks * 4 + (lane >> 4)) ^ (ra & 7);
        af[rt] = *(const v8s*)&As[ra * 64 + ca * 8];
      }
      for (int ct = 0; ct < 4; ++ct) {
        int rb = wc * 64 + ct * 16 + (lane & 15);
        int cb = (ks * 4 + (lane >> 4)) ^ (rb & 7);
        bf[ct] = *(const v8s*)&Bs[rb * 64 + cb * 8];
      }
      for (int rt = 0; rt < 2; ++rt)
        for (int ct = 0; ct < 4; ++ct)
          acc[rt][ct] = mfma16(af[rt], bf[ct], acc[rt][ct]);
    }
  };

  STAGE(0, 0);
  __syncthreads();
  for (int kt = 0; kt < 15; ++kt) {
    STAGE((kt + 1) & 1, (kt + 1) * 64);         // issue next tile
    COMPUTE(kt & 1);                            // compute current
    __syncthreads();                            // drain lands after compute
  }
  COMPUTE(1);
  __syncthreads();                              // LDS reuse for epilogue

  if (bn < 16) {
    // row-major restage S[64][128], chunk XOR (col>>3)^(m&7); coalesced stores
    for (int ct = 0; ct < 4; ++ct) {
      int col = wc * 64 + ct * 16 + (lane & 15);
      for (int rt = 0; rt < 2; ++rt)
        for (int j = 0; j < 4; ++j) {
          int m = wr * 32 + rt * 16 + ((lane >> 4) << 2) + j;
          S[m * 128 + (((col >> 3) ^ (m & 7)) << 3) + (col & 7)] = bf16bits(acc[rt][ct][j]);
        }
    }
    __syncthreads();
    for (int i = 0; i < 4; ++i) {
      int c = i * 256 + tid;                    // 1024 chunks: 64 rows x 16
      int m = c >> 4, c8 = c & 15;
      v8s v = *(const v8s*)&S[m * 128 + ((c8 ^ (m & 7)) << 3)];
      *(v8s*)&Cq[(size_t)(bm * 64 + m) * 2048 + bn * 128 + c8 * 8] = v;
    }
  } else {
    // transposed restage ST[128][64], chunk XOR (m>>3)^(n&7)
    for (int ct = 0; ct < 4; ++ct) {
      int n = wc * 64 + ct * 16 + (lane & 15);
      for (int rt = 0; rt < 2; ++rt) {
        int m0 = wr * 32 + rt * 16 + ((lane >> 4) << 2);
        ushort4 p4;
        p4.x = bf16bits(acc[rt][ct][0]); p4.y = bf16bits(acc[rt][ct][1]);
        p4.z = bf16bits(acc[rt][ct][2]); p4.w = bf16bits(acc[rt][ct][3]);
        *(ushort4*)&S[n * 64 + (((m0 >> 3) ^ (n & 7)) << 3) + (m0 & 7)] = p4;
      }
    }
    __syncthreads();
    int b = bm >> 5, s0 = (bm & 31) * 64;
    for (int i = 0; i < 4; ++i) {
      int c = i * 256 + tid;                    // 1024 chunks: 128 n x 8 m-chunks
      int n = c >> 3, c8 = c & 7;
      v8s v = *(const v8s*)&S[n * 64 + ((c8 ^ (n & 7)) << 3)];
      int nn = bn * 128 + n - 2048;             // v-col 0..1023
      int head = nn >> 6, d = nn & 63;
      *(v8s*)&VTh[(size_t)((b * 16 + head) * 64 + d) * 2048 + s0 + c8 * 8] = v;
    }
  }
}

// ---------------- attention: per (bh, 64 q-rows) block ----------------
// 4 waves x 16 q-rows. KBLK=64, K/V double-buffered + stage-ahead, one
// barrier/iter. P via LDS (round-3 structure), truncation bf16 pack.
__global__ __launch_bounds__(256) void attn_kernel(const unsigned short* __restrict__ Cq,
                                                   const unsigned short* __restrict__ VTh,
                                                   float* __restrict__ out) {
  __shared__ __align__(16) unsigned short Qs[64 * 64];     // [q][d]
  __shared__ __align__(16) unsigned short Ks[2][64 * 64];  // [key][d]
  __shared__ __align__(16) unsigned short Vs[2][64 * 64];  // [d][key]
  __shared__ __align__(16) unsigned short Ps[64 * 64];     // [q][key]
  int qb = blockIdx.x, bh = blockIdx.y;
  int tid = threadIdx.x, lane = tid & 63, wave = tid >> 6;
  int wq = wave * 16;
  int b = bh >> 4, h = bh & 15;

  const unsigned short* Qg = Cq + (size_t)(b * 2048 + qb * 64) * 2048 + h * 64;
  const unsigned short* Kg = Cq + (size_t)(b * 2048) * 2048 + 1024 + h * 64;
  const unsigned short* Vg = VTh + (size_t)bh * 64 * 2048;

  for (int i = 0; i < 2; ++i) {                  // Q tile + K/V tile 0
    int e = i * 256 + tid;
    int row = e >> 3, cc = e & 7;
    int sc = cc ^ (row & 7);
    GLD16(Qg + (size_t)row * 2048 + sc * 8, (char*)Qs + (i * 256 + wave * 64) * 16);
    GLD16(Kg + (size_t)row * 2048 + sc * 8, (char*)Ks[0] + (i * 256 + wave * 64) * 16);
    GLD16(Vg + row * 2048 + sc * 8, (char*)Vs[0] + (i * 256 + wave * 64) * 16);
  }
  __syncthreads();

  v8s qf[2];
  for (int ks = 0; ks < 2; ++ks) {
    int rq = wq + (lane & 15);
    int cq = (ks * 4 + (lane >> 4)) ^ (rq & 7);
    qf[ks] = *(const v8s*)&Qs[rq * 64 + cq * 8];
  }

  v4f oacc[4];
  for (int j = 0; j < 4; ++j) oacc[j] = (v4f){0.f, 0.f, 0.f, 0.f};
  float rsum[4] = {};

  for (int kt = 0; kt < 32; ++kt) {
    int cur = kt & 1;
    if (kt < 31) {                               // stage next K/V tile
      for (int i = 0; i < 2; ++i) {
        int e = i * 256 + tid;
        int row = e >> 3, cc = e & 7;
        int sc = cc ^ (row & 7);
        GLD16(Kg + (size_t)((kt + 1) * 64 + row) * 2048 + sc * 8,
              (char*)Ks[cur ^ 1] + (i * 256 + wave * 64) * 16);
        GLD16(Vg + row * 2048 + (kt + 1) * 64 + sc * 8,
              (char*)Vs[cur ^ 1] + (i * 256 + wave * 64) * 16);
      }
    }

    // scores = Q . K^T  (per wave: 1 q-tile x 4 key-tiles)
    v4f sacc[4];
    for (int j = 0; j < 4; ++j) sacc[j] = (v4f){0.f, 0.f, 0.f, 0.f};
    for (int ks = 0; ks < 2; ++ks) {
      v8s kf[4];
      for (int ct = 0; ct < 4; ++ct) {
        int rk = ct * 16 + (lane & 15);
        int ck = (ks * 4 + (lane >> 4)) ^ (rk & 7);
        kf[ct] = *(const v8s*)&Ks[cur][rk * 64 + ck * 8];
      }
      for (int ct = 0; ct < 4; ++ct)
        sacc[ct] = mfma16(qf[ks], kf[ct], sacc[ct]);
    }

    // P = exp(scale*S); rsum in f32; stage P to LDS (bf16 truncation pack)
    for (int ct = 0; ct < 4; ++ct)
      for (int j = 0; j < 4; ++j) {
        float p = __expf(sacc[ct][j] * 0.03125f);
        rsum[j] += p;
        union { float f; unsigned int u; } cv; cv.f = p;
        int prow = wq + ((lane >> 4) << 2) + j;
        int col = ct * 16 + (lane & 15);
        Ps[prow * 64 + (((col >> 3) ^ (prow & 7)) << 3) + (col & 7)] =
            (unsigned short)(cv.u >> 16);
      }
    // same-wave DS ordering: no barrier needed (P rows are wave-private)

    // O += P . V   (reduction over 64 keys)
    for (int ks4 = 0; ks4 < 2; ++ks4) {
      v8s pa, vb[4];
      int rp = wq + (lane & 15);
      int cp = (ks4 * 4 + (lane >> 4)) ^ (rp & 7);
      pa = *(const v8s*)&Ps[rp * 64 + cp * 8];
      for (int dt = 0; dt < 4; ++dt) {
        int rv = dt * 16 + (lane & 15);
        int cv2 = (ks4 * 4 + (lane >> 4)) ^ (rv & 7);
        vb[dt] = *(const v8s*)&Vs[cur][rv * 64 + cv2 * 8];
      }
      for (int dt = 0; dt < 4; ++dt)
        oacc[dt] = mfma16(pa, vb[dt], oacc[dt]);
    }
    __syncthreads();                             // drain next-tile loads; free cur
  }

  // complete row sums across the 16-lane col groups
  for (int j = 0; j < 4; ++j) {
    float v = rsum[j];
    v += __shfl_xor(v, 1, 64);
    v += __shfl_xor(v, 2, 64);
    v += __shfl_xor(v, 4, 64);
    v += __shfl_xor(v, 8, 64);
    rsum[j] = v;
  }

  for (int dt = 0; dt < 4; ++dt) {
    int q = qb * 64 + wq + ((lane >> 4) << 2);
    int d = h * 64 + dt * 16 + (lane & 15);
    for (int j = 0; j < 4; ++j)
      out[(size_t)(b * 2048 + q + j) * 1024 + d] = oacc[dt][j] / rsum[j];
  }
}

extern "C" void kernel_launch(void* const* d_in, const int* in_sizes, int n_in,
                              void* d_out, int out_size, void* d_ws, size_t ws_size,
                              hipStream_t stream) {
  const float* x = (const float*)d_in[0];   // [2,2048,1024]
  const float* w = (const float*)d_in[1];   // [1024,3072]
  float* out = (float*)d_out;

  char* ws = (char*)d_ws;
  unsigned short* xb = (unsigned short*)ws;                  // [4096][1024] bf16, 8 MB
  unsigned short* wT = (unsigned short*)(ws + 8388608);      // [3072][1024] bf16, 6 MB
  unsigned short* Cq = (unsigned short*)(ws + 14680064);     // [4096][2048] bf16, 16 MB (Q|K)
  unsigned short* VT = (unsigned short*)(ws + 31457280);     // [32][64][2048] bf16, 8 MB

  cvt_x_kernel<<<4096, 256, 0, stream>>>((const float4*)x, (ushort4*)xb, 1048576);
  cvt_wT_kernel<<<dim3(96, 32), 256, 0, stream>>>(w, wT);
  qkv_gemm<<<dim3(64, 24), 256, 0, stream>>>(xb, wT, Cq, VT);
  attn_kernel<<<dim3(32, 32), 256, 0, stream>>>(Cq, VT, out);
}